// Round 16
// baseline (506.906 us; speedup 1.0000x reference)
//
#include <hip/hip_runtime.h>
#include <hip/hip_bf16.h>
#include <cstdint>
#include <cstddef>

typedef short short8 __attribute__((ext_vector_type(8)));
typedef float float4_ __attribute__((ext_vector_type(4)));
typedef unsigned int uint4_ __attribute__((ext_vector_type(4)));
typedef unsigned int uint2_ __attribute__((ext_vector_type(2)));

#define DEVI static __device__ __forceinline__

DEVI unsigned short f2bf(float f) {
  union { float f; unsigned u; } v; v.f = f;
  return (unsigned short)((v.u + 0x7FFFu + ((v.u >> 16) & 1u)) >> 16);
}
DEVI unsigned pack2bf(float a, float b) {
  return (unsigned)f2bf(a) | ((unsigned)f2bf(b) << 16);
}
// Compiler-cast versions (lower to v_cvt_pk_bf16_f32 on gfx950; same RNE rounding).
DEVI unsigned short f2bfc(float f) {
  __hip_bfloat16 h = __float2bfloat16(f);
  union { __hip_bfloat16 h1; unsigned short u; } cv; cv.h1 = h; return cv.u;
}
DEVI unsigned pack2bfc(float a, float b) {
  float2 f2; f2.x = a; f2.y = b;
  __hip_bfloat162 h = __float22bfloat162_rn(f2);
  union { __hip_bfloat162 h2; unsigned u; } cv; cv.h2 = h; return cv.u;
}
DEVI float bf2f(unsigned short h) {
  union { unsigned u; float f; } v; v.u = ((unsigned)h) << 16;
  return v.f;
}
DEVI float gelu_f(float x) {
  float u = x * (0.7978845608f + 0.0356774081f * x * x);
  float e = exp2f(-2.8853900818f * u);           // = exp(-2u)
  return x * __builtin_amdgcn_rcpf(1.0f + e);    // arg >= 1, no NaN
}

#define SCALE_Q 0.17677669529663687f  // 32^-0.5

// ---------------- K0: weight prep ----------------
__global__ __launch_bounds__(256) void k_prep(
    const float* __restrict__ qkv_w, const float* __restrict__ qkv_b,
    const float* __restrict__ proj_w, const float* __restrict__ mlp_w1,
    const float* __restrict__ mlp_w2, const float* __restrict__ relt,
    unsigned short* __restrict__ qkvWT, unsigned short* __restrict__ projWT,
    unsigned short* __restrict__ w1T, unsigned short* __restrict__ w2T,
    float* __restrict__ qkv_b_s, float* __restrict__ bias_attn) {
  int i = blockIdx.x * 256 + threadIdx.x;
  if (i < 110592) { int n = i / 192, k = i - n * 192;
    float v = qkv_w[k * 576 + n]; if (n < 192) v *= SCALE_Q;
    qkvWT[i] = f2bf(v); return; }
  i -= 110592;
  if (i < 576) { qkv_b_s[i] = qkv_b[i] * (i < 192 ? SCALE_Q : 1.0f); return; }
  i -= 576;
  if (i < 36864) { int n = i / 192, k = i - n * 192;
    projWT[i] = f2bf(proj_w[k * 192 + n]); return; }
  i -= 36864;
  if (i < 147456) { int n = i / 192, k = i - n * 192;
    w1T[i] = f2bf(mlp_w1[k * 768 + n]); return; }
  i -= 147456;
  if (i < 147456) { int n = i / 768, k = i - n * 768;
    w2T[i] = f2bf(mlp_w2[k * 192 + n]); return; }
  i -= 147456;
  if (i < 24576) {
    int h = i >> 12, nm = i & 4095, n = nm >> 6, m = nm & 63;
    int dr = (n >> 3) - (m >> 3) + 7, dc = (n & 7) - (m & 7) + 7;
    bias_attn[i] = relt[(dr * 15 + dc) * 6 + h];
  }
}

// ---------------- K1a: dwconv3x3 + residual + roll -> temp[b][c][h][w] ----------------
__global__ __launch_bounds__(256) void k_conv(
    const float* __restrict__ x, const float* __restrict__ convw,
    unsigned short* __restrict__ temp) {
  __shared__ float s_in[66 * 128];
  int bx = blockIdx.x;
  int c = bx >> 1, seg = bx & 1, b = blockIdx.y;
  int h0 = seg * 64;
  int t = threadIdx.x;
  const float* xp = x + ((size_t)(b * 192 + c)) * 16384;
  #pragma unroll
  for (int i = 0; i < 9; ++i) {
    int q = t + i * 256;
    if (q < 2112) {
      int srow = q >> 5, chunk = q & 31;
      float4_ v = *(const float4_*)(xp + ((h0 + 3 + srow) & 127) * 128 + chunk * 4);
      *(float4_*)(s_in + srow * 128 + chunk * 4) = v;
    }
  }
  float cw9[9];
  #pragma unroll
  for (int i = 0; i < 9; ++i) cw9[i] = convw[c * 9 + i];
  __syncthreads();
  int r2 = t >> 7;
  int wp = t & 127;
  int w_true = (wp + 4) & 127;
  float mw0 = (w_true != 0) ? 1.f : 0.f;
  float mw2 = (w_true != 127) ? 1.f : 0.f;
  int wl0 = (w_true + 127) & 127, wl2 = (w_true + 1) & 127;
  unsigned short* tp = temp + ((size_t)(b * 192 + c)) * 16384;
  #pragma unroll 4
  for (int it = 0; it < 32; ++it) {
    int r = it * 2 + r2;
    int h_true = (h0 + 4 + r) & 127;
    float mh0 = (h_true != 0) ? 1.f : 0.f;
    float mh2 = (h_true != 127) ? 1.f : 0.f;
    const float* row0 = s_in + r * 128;
    const float* row1 = row0 + 128;
    const float* row2 = row1 + 128;
    float acc = row1[w_true];  // residual
    acc = fmaf(cw9[0], mh0 * mw0 * row0[wl0], acc);
    acc = fmaf(cw9[1], mh0 * row0[w_true], acc);
    acc = fmaf(cw9[2], mh0 * mw2 * row0[wl2], acc);
    acc = fmaf(cw9[3], mw0 * row1[wl0], acc);
    acc = fmaf(cw9[4], row1[w_true], acc);
    acc = fmaf(cw9[5], mw2 * row1[wl2], acc);
    acc = fmaf(cw9[6], mh2 * mw0 * row2[wl0], acc);
    acc = fmaf(cw9[7], mh2 * row2[w_true], acc);
    acc = fmaf(cw9[8], mh2 * mw2 * row2[wl2], acc);
    tp[(size_t)(h0 + r) * 128 + wp] = f2bf(acc);
  }
}

// ---------------- K1b: window-transpose + LN1: temp -> xw, a (R14 version) ----------------
__global__ __launch_bounds__(256) void k_lnw(
    const unsigned short* __restrict__ temp, const float* __restrict__ g1,
    const float* __restrict__ b1, unsigned short* __restrict__ xw,
    unsigned short* __restrict__ a) {
  __shared__ unsigned short sT[192 * 128];  // [c][tok] 48 KB
  __shared__ float s_g[192], s_b[192];
  int t = threadIdx.x;
  for (int i = t; i < 192; i += 256) { s_g[i] = g1[i]; s_b[i] = b1[i]; }
  int wj0 = blockIdx.x * 2, wi = blockIdx.y, b = blockIdx.z;
  const unsigned short* tb = temp + (size_t)b * (192 * 16384) + (wi * 8) * 128 + wj0 * 8;
  #pragma unroll
  for (int i = 0; i < 12; ++i) {
    int id = t + i * 256;
    int c = id >> 4, rem = id & 15, r = rem >> 1, piece = rem & 1;
    short8 v = *(const short8*)(tb + (size_t)c * 16384 + r * 128 + piece * 8);
    *(short8*)(sT + c * 128 + piece * 64 + r * 8) = v;
  }
  __syncthreads();
  int tok = t >> 1, half = t & 1, c0 = half * 96;
  size_t gtok = ((size_t)(b * 256 + wi * 16 + wj0 + (tok >> 6))) * 64 + (tok & 63);
  unsigned short* xwp = xw + gtok * 192 + c0;
  float sum = 0.f, sq = 0.f;
  #pragma unroll
  for (int j8 = 0; j8 < 12; ++j8) {
    unsigned short raw[8];
    unsigned pk[4];
    #pragma unroll
    for (int e = 0; e < 8; ++e) {
      unsigned short rv = sT[(c0 + j8 * 8 + e) * 128 + tok];
      raw[e] = rv;
      float x = bf2f(rv);
      sum += x; sq = fmaf(x, x, sq);
    }
    #pragma unroll
    for (int k = 0; k < 4; ++k) pk[k] = (unsigned)raw[2 * k] | ((unsigned)raw[2 * k + 1] << 16);
    uint4_ pv = { pk[0], pk[1], pk[2], pk[3] };
    *(uint4_*)(xwp + j8 * 8) = pv;
  }
  sum += __shfl_xor(sum, 1);
  sq  += __shfl_xor(sq, 1);
  float mu = sum * (1.f / 192.f);
  float var = sq * (1.f / 192.f) - mu * mu;
  float rs = rsqrtf(var + 1e-5f);
  unsigned short* ap = a + gtok * 192 + c0;
  #pragma unroll
  for (int j8 = 0; j8 < 12; ++j8) {
    unsigned pk[4];
    #pragma unroll
    for (int k = 0; k < 4; ++k) {
      int c = c0 + j8 * 8 + k * 2;
      float v0 = (bf2f(sT[c * 128 + tok]) - mu) * rs * s_g[c] + s_b[c];
      float v1 = (bf2f(sT[(c + 1) * 128 + tok]) - mu) * rs * s_g[c + 1] + s_b[c + 1];
      pk[k] = pack2bf(v0, v1);
    }
    uint4_ pv = { pk[0], pk[1], pk[2], pk[3] };
    *(uint4_*)(ap + j8 * 8) = pv;
  }
}

// ---------------- K2+K3 fused: QK-merged + V-separate GEMM + windowed attention ----------------
// 6 waves (1/head), 72KB LDS, (384,1). QK phase peak ~153 regs -> 3 waves/SIMD ->
// 2 blocks/CU restored (merged-QKV's 206-reg peak forced 1 block). Per-sel ks order
// unchanged -> bit-identical.
__global__ __launch_bounds__(384, 1) void k_qkvattn(
    const unsigned short* __restrict__ a, const unsigned short* __restrict__ wT,
    const float* __restrict__ qbias, const float* __restrict__ biasAll,
    unsigned short* __restrict__ outO) {
  __shared__ __align__(16) unsigned short sQK[6][4096];  // per head: Q[64][32] | K[64][32]; later P[64][64]
  __shared__ __align__(16) unsigned short sVT[6][2048];  // per head: V^T [32][64]
  int t = threadIdx.x, lane = t & 63, head = t / 64;
  int win = blockIdx.x;
  int wi = (win >> 4) & 15, wj = win & 15;
  int lrow = lane & 15, lkgrp = lane >> 4, lk = lkgrp * 8;
  const unsigned short* aWin = a + (size_t)win * (64 * 192);
  const unsigned short* wbase = wT + (size_t)head * 32 * 192;
  char* qk = (char*)sQK[head];
  char* vt = (char*)sVT[head];

  // ---- QK merged GEMM: acc[sel][nb][mi], sel in {0,1} ----
  {
    float4_ acc[2][2][4];
    #pragma unroll
    for (int s = 0; s < 2; ++s)
      #pragma unroll
      for (int nb = 0; nb < 2; ++nb)
        #pragma unroll
        for (int mi = 0; mi < 4; ++mi) acc[s][nb][mi] = (float4_){0.f, 0.f, 0.f, 0.f};
    short8 bwA[4], bwB[4], af0[4], af1[4];
    #pragma unroll
    for (int sn = 0; sn < 4; ++sn)
      bwA[sn] = *(const short8*)(wbase + (size_t)((sn >> 1) * 192 + (sn & 1) * 16 + lrow) * 192 + lk);
    #pragma unroll
    for (int mi = 0; mi < 4; ++mi)
      af0[mi] = *(const short8*)(aWin + (size_t)(mi * 16 + lrow) * 192 + lk);
    #pragma unroll
    for (int sn = 0; sn < 4; ++sn)
      bwB[sn] = *(const short8*)(wbase + (size_t)((sn >> 1) * 192 + (sn & 1) * 16 + lrow) * 192 + 32 + lk);
    #pragma unroll
    for (int mi = 0; mi < 4; ++mi)
      af1[mi] = *(const short8*)(aWin + (size_t)(mi * 16 + lrow) * 192 + 32 + lk);
    #pragma unroll
    for (int ks = 0; ks < 6; ++ks) {
      #pragma unroll
      for (int mi = 0; mi < 4; ++mi) {
        short8 a_ = (ks & 1) ? af1[mi] : af0[mi];
        #pragma unroll
        for (int sn = 0; sn < 4; ++sn) {
          short8 b_ = (ks & 1) ? bwB[sn] : bwA[sn];
          acc[sn >> 1][sn & 1][mi] =
              __builtin_amdgcn_mfma_f32_16x16x32_bf16(b_, a_, acc[sn >> 1][sn & 1][mi], 0, 0, 0);
        }
      }
      if (ks < 4) {
        int kc = (ks + 2) * 32 + lk;
        #pragma unroll
        for (int sn = 0; sn < 4; ++sn) {
          short8 nv = *(const short8*)(wbase + (size_t)((sn >> 1) * 192 + (sn & 1) * 16 + lrow) * 192 + kc);
          if (ks & 1) bwB[sn] = nv; else bwA[sn] = nv;
        }
        #pragma unroll
        for (int mi = 0; mi < 4; ++mi) {
          short8 nv = *(const short8*)(aWin + (size_t)(mi * 16 + lrow) * 192 + kc);
          if (ks & 1) af1[mi] = nv; else af0[mi] = nv;
        }
      }
    }
    // writeout Q,K: D[d = nb*16+lkgrp*4+e][tok = mi*16+lrow]
    #pragma unroll
    for (int sel = 0; sel < 2; ++sel) {
      #pragma unroll
      for (int nb = 0; nb < 2; ++nb) {
        float4_ b4 = *(const float4_*)(qbias + sel * 192 + head * 32 + nb * 16 + lkgrp * 4);
        int dsub2 = (nb * 16 + lkgrp * 4) * 2;
        #pragma unroll
        for (int mi = 0; mi < 4; ++mi) {
          int tok = mi * 16 + lrow;
          uint2_ pv = { pack2bfc(acc[sel][nb][mi][0] + b4[0], acc[sel][nb][mi][1] + b4[1]),
                        pack2bfc(acc[sel][nb][mi][2] + b4[2], acc[sel][nb][mi][3] + b4[3]) };
          *(uint2_*)(qk + sel * 4096 + ((tok * 64 + dsub2) ^ ((tok & 7) << 4))) = pv;
        }
      }
    }
  }
  // ---- V GEMM (separate pass; af reloaded, L2-hot) ----
  {
    float4_ acc[2][4];
    #pragma unroll
    for (int nb = 0; nb < 2; ++nb)
      #pragma unroll
      for (int mi = 0; mi < 4; ++mi) acc[nb][mi] = (float4_){0.f, 0.f, 0.f, 0.f};
    short8 vwA[2], vwB[2], af0[4], af1[4];
    #pragma unroll
    for (int nb = 0; nb < 2; ++nb)
      vwA[nb] = *(const short8*)(wbase + (size_t)(2 * 192 + nb * 16 + lrow) * 192 + lk);
    #pragma unroll
    for (int mi = 0; mi < 4; ++mi)
      af0[mi] = *(const short8*)(aWin + (size_t)(mi * 16 + lrow) * 192 + lk);
    #pragma unroll
    for (int nb = 0; nb < 2; ++nb)
      vwB[nb] = *(const short8*)(wbase + (size_t)(2 * 192 + nb * 16 + lrow) * 192 + 32 + lk);
    #pragma unroll
    for (int mi = 0; mi < 4; ++mi)
      af1[mi] = *(const short8*)(aWin + (size_t)(mi * 16 + lrow) * 192 + 32 + lk);
    #pragma unroll
    for (int ks = 0; ks < 6; ++ks) {
      #pragma unroll
      for (int mi = 0; mi < 4; ++mi) {
        short8 a_ = (ks & 1) ? af1[mi] : af0[mi];
        #pragma unroll
        for (int nb = 0; nb < 2; ++nb) {
          short8 b_ = (ks & 1) ? vwB[nb] : vwA[nb];
          acc[nb][mi] = __builtin_amdgcn_mfma_f32_16x16x32_bf16(b_, a_, acc[nb][mi], 0, 0, 0);
        }
      }
      if (ks < 4) {
        int kc = (ks + 2) * 32 + lk;
        #pragma unroll
        for (int nb = 0; nb < 2; ++nb) {
          short8 nv = *(const short8*)(wbase + (size_t)(2 * 192 + nb * 16 + lrow) * 192 + kc);
          if (ks & 1) vwB[nb] = nv; else vwA[nb] = nv;
        }
        #pragma unroll
        for (int mi = 0; mi < 4; ++mi) {
          short8 nv = *(const short8*)(aWin + (size_t)(mi * 16 + lrow) * 192 + kc);
          if (ks & 1) af1[mi] = nv; else af0[mi] = nv;
        }
      }
    }
    #pragma unroll
    for (int nb = 0; nb < 2; ++nb) {
      float4_ b4 = *(const float4_*)(qbias + 384 + head * 32 + nb * 16 + lkgrp * 4);
      #pragma unroll
      for (int mi = 0; mi < 4; ++mi) {
        int tok = mi * 16 + lrow;
        #pragma unroll
        for (int e = 0; e < 4; ++e) {
          int d = nb * 16 + lkgrp * 4 + e;
          *(unsigned short*)(vt + ((d * 128 + tok * 2) ^ ((d & 7) << 4))) =
              f2bfc(acc[nb][mi][e] + b4[e]);
        }
      }
    }
  }

  // --- S = Q K^T ---
  short8 kf[4];
  #pragma unroll
  for (int ni = 0; ni < 4; ++ni) {
    int tokk = ni * 16 + lrow;
    kf[ni] = *(const short8*)(qk + 4096 + ((tokk * 64 + lk * 2) ^ ((tokk & 7) << 4)));
  }
  float4_ s[4][4];
  __builtin_amdgcn_s_setprio(1);
  #pragma unroll
  for (int mi = 0; mi < 4; ++mi) {
    int tokq = mi * 16 + lrow;
    short8 qf = *(const short8*)(qk + ((tokq * 64 + lk * 2) ^ ((tokq & 7) << 4)));
    #pragma unroll
    for (int ni = 0; ni < 4; ++ni) {
      s[mi][ni] = (float4_){0.f, 0.f, 0.f, 0.f};
      s[mi][ni] = __builtin_amdgcn_mfma_f32_16x16x32_bf16(qf, kf[ni], s[mi][ni], 0, 0, 0);
    }
  }
  __builtin_amdgcn_s_setprio(0);
  // --- softmax -> P over qk region ---
  const float* bh = biasAll + head * 4096;
  bool wi15 = (wi == 15), wj15 = (wj == 15);
  bool edge = wi15 || wj15;
  #pragma unroll
  for (int mi = 0; mi < 4; ++mi) {
    #pragma unroll
    for (int e = 0; e < 4; ++e) {
      int row = mi * 16 + lkgrp * 4 + e;
      int rcls = (wi15 ? ((row >> 3) >= 4 ? 2 : 1) : 0) * 3 +
                 (wj15 ? ((row & 7) >= 4 ? 2 : 1) : 0);
      float v[4];
      #pragma unroll
      for (int ni = 0; ni < 4; ++ni) {
        int col = ni * 16 + lrow;
        float xv = s[mi][ni][e] + bh[row * 64 + col];
        if (edge) {
          int ccls = (wi15 ? ((col >> 3) >= 4 ? 2 : 1) : 0) * 3 +
                     (wj15 ? ((col & 7) >= 4 ? 2 : 1) : 0);
          if (ccls != rcls) xv -= 100.f;
        }
        v[ni] = xv;
      }
      float mx = fmaxf(fmaxf(v[0], v[1]), fmaxf(v[2], v[3]));
      mx = fmaxf(mx, __shfl_xor(mx, 1));
      mx = fmaxf(mx, __shfl_xor(mx, 2));
      mx = fmaxf(mx, __shfl_xor(mx, 4));
      mx = fmaxf(mx, __shfl_xor(mx, 8));
      float sm = 0.f;
      #pragma unroll
      for (int ni = 0; ni < 4; ++ni) { v[ni] = __expf(v[ni] - mx); sm += v[ni]; }
      sm += __shfl_xor(sm, 1);
      sm += __shfl_xor(sm, 2);
      sm += __shfl_xor(sm, 4);
      sm += __shfl_xor(sm, 8);
      float inv = 1.f / sm;
      #pragma unroll
      for (int ni = 0; ni < 4; ++ni) {
        int col = ni * 16 + lrow;
        *(unsigned short*)(qk + ((row * 128 + col * 2) ^ ((row & 7) << 4))) = f2bfc(v[ni] * inv);
      }
    }
  }
  // --- O^T = V^T @ P^T ---
  float4_ o[2][4];
  #pragma unroll
  for (int db = 0; db < 2; ++db)
    #pragma unroll
    for (int qb2 = 0; qb2 < 4; ++qb2) o[db][qb2] = (float4_){0.f, 0.f, 0.f, 0.f};
  __builtin_amdgcn_s_setprio(1);
  #pragma unroll
  for (int kk = 0; kk < 2; ++kk) {
    int ktok = kk * 32 + lk;
    short8 vf[2], pf[4];
    #pragma unroll
    for (int db = 0; db < 2; ++db) {
      int d = db * 16 + lrow;
      vf[db] = *(const short8*)(vt + ((d * 128 + ktok * 2) ^ ((d & 7) << 4)));
    }
    #pragma unroll
    for (int qb2 = 0; qb2 < 4; ++qb2) {
      int rq = qb2 * 16 + lrow;
      pf[qb2] = *(const short8*)(qk + ((rq * 128 + ktok * 2) ^ ((rq & 7) << 4)));
    }
    #pragma unroll
    for (int db = 0; db < 2; ++db)
      #pragma unroll
      for (int qb2 = 0; qb2 < 4; ++qb2)
        o[db][qb2] = __builtin_amdgcn_mfma_f32_16x16x32_bf16(vf[db], pf[qb2], o[db][qb2], 0, 0, 0);
  }
  __builtin_amdgcn_s_setprio(0);
  unsigned short* ob = outO + (size_t)win * (64 * 192);
  #pragma unroll
  for (int qb2 = 0; qb2 < 4; ++qb2)
    #pragma unroll
    for (int db = 0; db < 2; ++db) {
      unsigned lo = pack2bfc(o[db][qb2][0], o[db][qb2][1]);
      unsigned hi = pack2bfc(o[db][qb2][2], o[db][qb2][3]);
      uint2_ pv = { lo, hi };
      *(uint2_*)(ob + (size_t)(qb2 * 16 + lrow) * 192 + head * 32 + db * 16 + lkgrp * 4) = pv;
    }
}

// ---------------- K4: proj + residual + LN2 + MLP(GELU) + residual + un-window ----------------
// (256,2). w1 phase accumulates ALL ni at once (h1[4][3]) -> sH reads 72->24 per chunk;
// rolling per-ks w1 weight buffers; next-chunk preload hidden under w2 phase. sB2 dbuf.
__global__ __launch_bounds__(256, 2) void k_mlp(
    const unsigned short* __restrict__ O, const unsigned short* __restrict__ xw,
    const unsigned short* __restrict__ projWT, const float* __restrict__ proj_b,
    const float* __restrict__ n2g, const float* __restrict__ n2b,
    const unsigned short* __restrict__ w1T, const float* __restrict__ mlpb1,
    const unsigned short* __restrict__ w2T, const float* __restrict__ mlpb2,
    float* __restrict__ y) {
  __shared__ __align__(16) unsigned short sH[64 * 192];
  __shared__ __align__(16) unsigned short sB2[2][64 * 192];
  __shared__ float sRed[64 * 8];
  __shared__ unsigned sTok[64];
  int t = threadIdx.x, lane = t & 63, wn = t >> 6;
  int lrow = lane & 15, lkgrp = lane >> 4, lk = lkgrp * 8;
  int blk = blockIdx.x;
  int b = blk >> 8, rem = blk & 255, ta = rem >> 3, tb_ = rem & 7;
  if (t < 64) {
    int rr = t >> 4, ss = t & 15;
    int h = ta * 4 + rr, w = tb_ * 16 + ss;
    int hp = (h + 124) & 127, wp = (w + 124) & 127;
    unsigned gtok = ((unsigned)(b * 256 + (hp >> 3) * 16 + (wp >> 3))) * 64 +
                    (hp & 7) * 8 + (wp & 7);
    sTok[t] = gtok * 192u;
  }
  __syncthreads();
  unsigned aoff[4];
  #pragma unroll
  for (int mi = 0; mi < 4; ++mi) aoff[mi] = sTok[mi * 16 + lrow];
  // ---- proj: rolling prefetch with gathered A rows ----
  float4_ tacc[4][3];
  #pragma unroll
  for (int mi = 0; mi < 4; ++mi)
    #pragma unroll
    for (int ni = 0; ni < 3; ++ni) tacc[mi][ni] = (float4_){0.f, 0.f, 0.f, 0.f};
  {
    short8 bP0[3][3], bP1[3][3], af0[4], af1[4];
    #pragma unroll
    for (int ni = 0; ni < 3; ++ni)
      #pragma unroll
      for (int k3 = 0; k3 < 3; ++k3)
        bP0[ni][k3] = *(const short8*)(projWT + (size_t)(wn * 48 + ni * 16 + lrow) * 192 + k3 * 32 + lk);
    #pragma unroll
    for (int mi = 0; mi < 4; ++mi)
      af0[mi] = *(const short8*)(O + aoff[mi] + lk);
    #pragma unroll
    for (int ni = 0; ni < 3; ++ni)
      #pragma unroll
      for (int k3 = 0; k3 < 3; ++k3)
        bP1[ni][k3] = *(const short8*)(projWT + (size_t)(wn * 48 + ni * 16 + lrow) * 192 + (3 + k3) * 32 + lk);
    #pragma unroll
    for (int mi = 0; mi < 4; ++mi)
      af1[mi] = *(const short8*)(O + aoff[mi] + 32 + lk);
    #pragma unroll
    for (int ks = 0; ks < 6; ++ks) {
      #pragma unroll
      for (int mi = 0; mi < 4; ++mi) {
        short8 a_ = (ks & 1) ? af1[mi] : af0[mi];
        #pragma unroll
        for (int ni = 0; ni < 3; ++ni) {
          short8 b_ = (ks < 3) ? bP0[ni][ks] : bP1[ni][ks - 3];
          tacc[mi][ni] = __builtin_amdgcn_mfma_f32_16x16x32_bf16(a_, b_, tacc[mi][ni], 0, 0, 0);
        }
      }
      if (ks < 4) {
        #pragma unroll
        for (int mi = 0; mi < 4; ++mi) {
          short8 nv = *(const short8*)(O + aoff[mi] + (ks + 2) * 32 + lk);
          if (ks & 1) af1[mi] = nv; else af0[mi] = nv;
        }
      }
    }
  }
  // ---- residual: batched gathered xw loads ----
  {
    unsigned roff[4][4];
    #pragma unroll
    for (int mi = 0; mi < 4; ++mi)
      #pragma unroll
      for (int e = 0; e < 4; ++e)
        roff[mi][e] = sTok[mi * 16 + lkgrp * 4 + e];
    unsigned short rxv[3][4][4];
    #pragma unroll
    for (int ni = 0; ni < 3; ++ni) {
      int col = wn * 48 + ni * 16 + lrow;
      #pragma unroll
      for (int mi = 0; mi < 4; ++mi)
        #pragma unroll
        for (int e = 0; e < 4; ++e)
          rxv[ni][mi][e] = xw[roff[mi][e] + col];
    }
    #pragma unroll
    for (int ni = 0; ni < 3; ++ni) {
      float pbv = proj_b[wn * 48 + ni * 16 + lrow];
      #pragma unroll
      for (int mi = 0; mi < 4; ++mi)
        #pragma unroll
        for (int e = 0; e < 4; ++e)
          tacc[mi][ni][e] += pbv + bf2f(rxv[ni][mi][e]);
    }
  }
  // ---- LN2 ----
  #pragma unroll
  for (int mi = 0; mi < 4; ++mi)
    #pragma unroll
    for (int e = 0; e < 4; ++e) {
      float s1 = tacc[mi][0][e] + tacc[mi][1][e] + tacc[mi][2][e];
      float s2 = tacc[mi][0][e] * tacc[mi][0][e] + tacc[mi][1][e] * tacc[mi][1][e] +
                 tacc[mi][2][e] * tacc[mi][2][e];
      s1 += __shfl_xor(s1, 1); s1 += __shfl_xor(s1, 2); s1 += __shfl_xor(s1, 4); s1 += __shfl_xor(s1, 8);
      s2 += __shfl_xor(s2, 1); s2 += __shfl_xor(s2, 2); s2 += __shfl_xor(s2, 4); s2 += __shfl_xor(s2, 8);
      if (lrow == 0) {
        int row = mi * 16 + lkgrp * 4 + e;
        sRed[row * 8 + wn * 2 + 0] = s1;
        sRed[row * 8 + wn * 2 + 1] = s2;
      }
    }
  __syncthreads();
  #pragma unroll
  for (int mi = 0; mi < 4; ++mi)
    #pragma unroll
    for (int e = 0; e < 4; ++e) {
      int row = mi * 16 + lkgrp * 4 + e;
      float s1 = sRed[row * 8] + sRed[row * 8 + 2] + sRed[row * 8 + 4] + sRed[row * 8 + 6];
      float s2 = sRed[row * 8 + 1] + sRed[row * 8 + 3] + sRed[row * 8 + 5] + sRed[row * 8 + 7];
      float mu = s1 * (1.f / 192.f);
      float var = s2 * (1.f / 192.f) - mu * mu;
      float rs = rsqrtf(var + 1e-5f);
      #pragma unroll
      for (int ni = 0; ni < 3; ++ni) {
        int col = wn * 48 + ni * 16 + lrow;
        float hv = (tacc[mi][ni][e] - mu) * rs * n2g[col] + n2b[col];
        *(unsigned short*)((char*)sH + ((row * 384 + col * 2) ^ ((row & 7) << 4))) = f2bfc(hv);
      }
    }
  __syncthreads();
  // ---- MLP: w1 all-ni accumulation, rolling per-ks weights; w2 half-batched; sB2 dbuf ----
  short8 wA[3], wB[3];
  #pragma unroll
  for (int ni = 0; ni < 3; ++ni)
    wA[ni] = *(const short8*)(w1T + (size_t)(wn * 48 + ni * 16 + lrow) * 192 + lk);
  #pragma unroll
  for (int ni = 0; ni < 3; ++ni)
    wB[ni] = *(const short8*)(w1T + (size_t)(wn * 48 + ni * 16 + lrow) * 192 + 32 + lk);
  #pragma unroll 1
  for (int ch = 0; ch < 4; ++ch) {
    char* sBc = (char*)sB2[ch & 1];
    float4_ h1[4][3];
    #pragma unroll
    for (int mi = 0; mi < 4; ++mi)
      #pragma unroll
      for (int ni = 0; ni < 3; ++ni) h1[mi][ni] = (float4_){0.f, 0.f, 0.f, 0.f};
    __builtin_amdgcn_s_setprio(1);
    #pragma unroll
    for (int ks = 0; ks < 6; ++ks) {
      int kb = ks * 32 + lk;
      #pragma unroll
      for (int mi = 0; mi < 4; ++mi) {
        int row = mi * 16 + lrow;
        short8 afv = *(const short8*)((const char*)sH + ((row * 384 + kb * 2) ^ ((row & 7) << 4)));
        #pragma unroll
        for (int ni = 0; ni < 3; ++ni) {
          short8 b_ = (ks & 1) ? wB[ni] : wA[ni];
          h1[mi][ni] = __builtin_amdgcn_mfma_f32_16x16x32_bf16(b_, afv, h1[mi][ni], 0, 0, 0);
        }
      }
      if (ks < 4) {
        int kc = (ks + 2) * 32 + lk;
        #pragma unroll
        for (int ni = 0; ni < 3; ++ni) {
          short8 nv = *(const short8*)(w1T + (size_t)(ch * 192 + wn * 48 + ni * 16 + lrow) * 192 + kc);
          if (ks & 1) wB[ni] = nv; else wA[ni] = nv;
        }
      }
    }
    __builtin_amdgcn_s_setprio(0);
    // gelu writeout: D[n = ni*16+lkgrp*4+e][tok = mi*16+lrow] -> packed 8B stores
    #pragma unroll
    for (int ni = 0; ni < 3; ++ni) {
      float4_ b4 = *(const float4_*)(mlpb1 + ch * 192 + wn * 48 + ni * 16 + lkgrp * 4);
      int nsub2 = (wn * 48 + ni * 16 + lkgrp * 4) * 2;
      #pragma unroll
      for (int mi = 0; mi < 4; ++mi) {
        int tok_ = mi * 16 + lrow;
        float g0 = gelu_f(h1[mi][ni][0] + b4[0]);
        float g1 = gelu_f(h1[mi][ni][1] + b4[1]);
        float g2 = gelu_f(h1[mi][ni][2] + b4[2]);
        float g3 = gelu_f(h1[mi][ni][3] + b4[3]);
        uint2_ pv = { pack2bfc(g0, g1), pack2bfc(g2, g3) };
        *(uint2_*)(sBc + ((tok_ * 384 + nsub2) ^ ((tok_ & 7) << 4))) = pv;
      }
    }
    // w2 weights (half-batched) + next-chunk w1 ks0/ks1 preload under this phase
    short8 cw0[3][3], cw1[3][3];
    #pragma unroll
    for (int ni = 0; ni < 3; ++ni)
      #pragma unroll
      for (int k3 = 0; k3 < 3; ++k3)
        cw0[ni][k3] = *(const short8*)(w2T + (size_t)(wn * 48 + ni * 16 + lrow) * 768 + ch * 192 + k3 * 32 + lk);
    __syncthreads();
    #pragma unroll
    for (int ni = 0; ni < 3; ++ni)
      #pragma unroll
      for (int k3 = 0; k3 < 3; ++k3)
        cw1[ni][k3] = *(const short8*)(w2T + (size_t)(wn * 48 + ni * 16 + lrow) * 768 + ch * 192 + (3 + k3) * 32 + lk);
    if (ch < 3) {
      int gb = (ch + 1) * 192 + wn * 48;
      #pragma unroll
      for (int ni = 0; ni < 3; ++ni)
        wA[ni] = *(const short8*)(w1T + (size_t)(gb + ni * 16 + lrow) * 192 + lk);
      #pragma unroll
      for (int ni = 0; ni < 3; ++ni)
        wB[ni] = *(const short8*)(w1T + (size_t)(gb + ni * 16 + lrow) * 192 + 32 + lk);
    }
    __builtin_amdgcn_s_setprio(1);
    #pragma unroll
    for (int ks = 0; ks < 6; ++ks) {
      int kb = ks * 32 + lk;
      short8 af[4];
      #pragma unroll
      for (int mi = 0; mi < 4; ++mi) {
        int row = mi * 16 + lrow;
        af[mi] = *(const short8*)(sBc + ((row * 384 + kb * 2) ^ ((row & 7) << 4)));
      }
      #pragma unroll
      for (int mi = 0; mi < 4; ++mi)
        #pragma unroll
        for (int ni = 0; ni < 3; ++ni) {
          short8 b_ = (ks < 3) ? cw0[ni][ks] : cw1[ni][ks - 3];
          tacc[mi][ni] = __builtin_amdgcn_mfma_f32_16x16x32_bf16(af[mi], b_, tacc[mi][ni], 0, 0, 0);
        }
    }
    __builtin_amdgcn_s_setprio(0);
    // no end-of-chunk barrier: sB2 double-buffered; reuse ordered by next chunk's pre-w2 barrier.
  }
  // ---- epilogue: +mlp_b2, aligned full-line y stores ----
  int wcol = tb_ * 16 + lkgrp * 4;
  #pragma unroll
  for (int ni = 0; ni < 3; ++ni) {
    int col = wn * 48 + ni * 16 + lrow;
    float b2v = mlpb2[col];
    #pragma unroll
    for (int mi = 0; mi < 4; ++mi) {
      int h = ta * 4 + mi;
      float4_ vv;
      #pragma unroll
      for (int e = 0; e < 4; ++e) vv[e] = tacc[mi][ni][e] + b2v;
      *(float4_*)(y + ((size_t)(b * 192 + col) * 128 + h) * 128 + wcol) = vv;
    }
  }
}

extern "C" void kernel_launch(void* const* d_in, const int* in_sizes, int n_in,
                              void* d_out, int out_size, void* d_ws, size_t ws_size,
                              hipStream_t stream) {
  (void)in_sizes; (void)n_in; (void)out_size;
  const float* x    = (const float*)d_in[0];
  const float* pcw  = (const float*)d_in[1];
  const float* n1g  = (const float*)d_in[2];
  const float* n1b  = (const float*)d_in[3];
  const float* qkvw = (const float*)d_in[4];
  const float* qkvb = (const float*)d_in[5];
  const float* pw   = (const float*)d_in[6];
  const float* pb   = (const float*)d_in[7];
  const float* relt = (const float*)d_in[8];
  const float* n2g  = (const float*)d_in[9];
  const float* n2b  = (const float*)d_in[10];
  const float* w1   = (const float*)d_in[11];
  const float* mb1  = (const float*)d_in[12];
  const float* w2   = (const float*)d_in[13];
  const float* mb2  = (const float*)d_in[14];
  float* y = (float*)d_out;
  char* ws = (char*)d_ws;
  size_t off = 0;
  auto carve = [&](size_t bytes) { void* p = ws + off; off += (bytes + 255) & ~(size_t)255; return p; };
  unsigned short* qkvWT  = (unsigned short*)carve(576 * 192 * 2);
  unsigned short* projWT = (unsigned short*)carve(192 * 192 * 2);
  unsigned short* w1T    = (unsigned short*)carve(768 * 192 * 2);
  unsigned short* w2T    = (unsigned short*)carve(192 * 768 * 2);
  float* qkv_b_s   = (float*)carve(576 * 4);
  float* bias_attn = (float*)carve(6 * 64 * 64 * 4);
  unsigned short* aBuf   = (unsigned short*)carve((size_t)131072 * 192 * 2);
  unsigned short* xwBuf  = (unsigned short*)carve((size_t)131072 * 192 * 2);
  unsigned short* temp   = (unsigned short*)carve((size_t)131072 * 192 * 2); // conv temp, then O
  if (off > ws_size) return;

  k_prep<<<dim3(1827), dim3(256), 0, stream>>>(qkvw, qkvb, pw, w1, w2, relt,
                                               qkvWT, projWT, w1T, w2T, qkv_b_s, bias_attn);
  k_conv<<<dim3(384, 8), dim3(256), 0, stream>>>(x, pcw, temp);
  k_lnw<<<dim3(8, 16, 8), dim3(256), 0, stream>>>(temp, n1g, n1b, xwBuf, aBuf);
  k_qkvattn<<<dim3(2048), dim3(384), 0, stream>>>(aBuf, qkvWT, qkv_b_s, bias_attn, temp);
  k_mlp<<<dim3(2048), dim3(256), 0, stream>>>(temp, xwBuf, projWT, pb, n2g, n2b,
                                              w1T, mb1, w2T, mb2, y);
}

// Round 17
// 484.065 us; speedup vs baseline: 1.0472x; 1.0472x over previous
//
#include <hip/hip_runtime.h>
#include <hip/hip_bf16.h>
#include <cstdint>
#include <cstddef>

typedef short short8 __attribute__((ext_vector_type(8)));
typedef float float4_ __attribute__((ext_vector_type(4)));
typedef unsigned int uint4_ __attribute__((ext_vector_type(4)));
typedef unsigned int uint2_ __attribute__((ext_vector_type(2)));

#define DEVI static __device__ __forceinline__

DEVI unsigned short f2bf(float f) {
  union { float f; unsigned u; } v; v.f = f;
  return (unsigned short)((v.u + 0x7FFFu + ((v.u >> 16) & 1u)) >> 16);
}
DEVI unsigned pack2bf(float a, float b) {
  return (unsigned)f2bf(a) | ((unsigned)f2bf(b) << 16);
}
// Compiler-cast versions (lower to v_cvt_pk_bf16_f32 on gfx950; same RNE rounding).
DEVI unsigned short f2bfc(float f) {
  __hip_bfloat16 h = __float2bfloat16(f);
  union { __hip_bfloat16 h1; unsigned short u; } cv; cv.h1 = h; return cv.u;
}
DEVI unsigned pack2bfc(float a, float b) {
  float2 f2; f2.x = a; f2.y = b;
  __hip_bfloat162 h = __float22bfloat162_rn(f2);
  union { __hip_bfloat162 h2; unsigned u; } cv; cv.h2 = h; return cv.u;
}
DEVI float bf2f(unsigned short h) {
  union { unsigned u; float f; } v; v.u = ((unsigned)h) << 16;
  return v.f;
}
DEVI float gelu_f(float x) {
  float u = x * (0.7978845608f + 0.0356774081f * x * x);
  float e = exp2f(-2.8853900818f * u);           // = exp(-2u)
  return x * __builtin_amdgcn_rcpf(1.0f + e);    // arg >= 1, no NaN
}

#define SCALE_Q 0.17677669529663687f  // 32^-0.5

// ---------------- K0: weight prep ----------------
__global__ __launch_bounds__(256) void k_prep(
    const float* __restrict__ qkv_w, const float* __restrict__ qkv_b,
    const float* __restrict__ proj_w, const float* __restrict__ mlp_w1,
    const float* __restrict__ mlp_w2, const float* __restrict__ relt,
    unsigned short* __restrict__ qkvWT, unsigned short* __restrict__ projWT,
    unsigned short* __restrict__ w1T, unsigned short* __restrict__ w2T,
    float* __restrict__ qkv_b_s, float* __restrict__ bias_attn) {
  int i = blockIdx.x * 256 + threadIdx.x;
  if (i < 110592) { int n = i / 192, k = i - n * 192;
    float v = qkv_w[k * 576 + n]; if (n < 192) v *= SCALE_Q;
    qkvWT[i] = f2bf(v); return; }
  i -= 110592;
  if (i < 576) { qkv_b_s[i] = qkv_b[i] * (i < 192 ? SCALE_Q : 1.0f); return; }
  i -= 576;
  if (i < 36864) { int n = i / 192, k = i - n * 192;
    projWT[i] = f2bf(proj_w[k * 192 + n]); return; }
  i -= 36864;
  if (i < 147456) { int n = i / 192, k = i - n * 192;
    w1T[i] = f2bf(mlp_w1[k * 768 + n]); return; }
  i -= 147456;
  if (i < 147456) { int n = i / 768, k = i - n * 768;
    w2T[i] = f2bf(mlp_w2[k * 192 + n]); return; }
  i -= 147456;
  if (i < 24576) {
    int h = i >> 12, nm = i & 4095, n = nm >> 6, m = nm & 63;
    int dr = (n >> 3) - (m >> 3) + 7, dc = (n & 7) - (m & 7) + 7;
    bias_attn[i] = relt[(dr * 15 + dc) * 6 + h];
  }
}

// ---------------- K1a: dwconv3x3 + residual + roll -> temp[b][c][h][w] ----------------
__global__ __launch_bounds__(256) void k_conv(
    const float* __restrict__ x, const float* __restrict__ convw,
    unsigned short* __restrict__ temp) {
  __shared__ float s_in[66 * 128];
  int bx = blockIdx.x;
  int c = bx >> 1, seg = bx & 1, b = blockIdx.y;
  int h0 = seg * 64;
  int t = threadIdx.x;
  const float* xp = x + ((size_t)(b * 192 + c)) * 16384;
  #pragma unroll
  for (int i = 0; i < 9; ++i) {
    int q = t + i * 256;
    if (q < 2112) {
      int srow = q >> 5, chunk = q & 31;
      float4_ v = *(const float4_*)(xp + ((h0 + 3 + srow) & 127) * 128 + chunk * 4);
      *(float4_*)(s_in + srow * 128 + chunk * 4) = v;
    }
  }
  float cw9[9];
  #pragma unroll
  for (int i = 0; i < 9; ++i) cw9[i] = convw[c * 9 + i];
  __syncthreads();
  int r2 = t >> 7;
  int wp = t & 127;
  int w_true = (wp + 4) & 127;
  float mw0 = (w_true != 0) ? 1.f : 0.f;
  float mw2 = (w_true != 127) ? 1.f : 0.f;
  int wl0 = (w_true + 127) & 127, wl2 = (w_true + 1) & 127;
  unsigned short* tp = temp + ((size_t)(b * 192 + c)) * 16384;
  #pragma unroll 4
  for (int it = 0; it < 32; ++it) {
    int r = it * 2 + r2;
    int h_true = (h0 + 4 + r) & 127;
    float mh0 = (h_true != 0) ? 1.f : 0.f;
    float mh2 = (h_true != 127) ? 1.f : 0.f;
    const float* row0 = s_in + r * 128;
    const float* row1 = row0 + 128;
    const float* row2 = row1 + 128;
    float acc = row1[w_true];  // residual
    acc = fmaf(cw9[0], mh0 * mw0 * row0[wl0], acc);
    acc = fmaf(cw9[1], mh0 * row0[w_true], acc);
    acc = fmaf(cw9[2], mh0 * mw2 * row0[wl2], acc);
    acc = fmaf(cw9[3], mw0 * row1[wl0], acc);
    acc = fmaf(cw9[4], row1[w_true], acc);
    acc = fmaf(cw9[5], mw2 * row1[wl2], acc);
    acc = fmaf(cw9[6], mh2 * mw0 * row2[wl0], acc);
    acc = fmaf(cw9[7], mh2 * row2[w_true], acc);
    acc = fmaf(cw9[8], mh2 * mw2 * row2[wl2], acc);
    tp[(size_t)(h0 + r) * 128 + wp] = f2bf(acc);
  }
}

// ---------------- K1b: window-transpose + LN1: temp -> xw, a ----------------
__global__ __launch_bounds__(256) void k_lnw(
    const unsigned short* __restrict__ temp, const float* __restrict__ g1,
    const float* __restrict__ b1, unsigned short* __restrict__ xw,
    unsigned short* __restrict__ a) {
  __shared__ unsigned short sT[192 * 128];  // [c][tok] 48 KB
  __shared__ float s_g[192], s_b[192];
  int t = threadIdx.x;
  for (int i = t; i < 192; i += 256) { s_g[i] = g1[i]; s_b[i] = b1[i]; }
  int wj0 = blockIdx.x * 2, wi = blockIdx.y, b = blockIdx.z;
  const unsigned short* tb = temp + (size_t)b * (192 * 16384) + (wi * 8) * 128 + wj0 * 8;
  #pragma unroll
  for (int i = 0; i < 12; ++i) {
    int id = t + i * 256;
    int c = id >> 4, rem = id & 15, r = rem >> 1, piece = rem & 1;
    short8 v = *(const short8*)(tb + (size_t)c * 16384 + r * 128 + piece * 8);
    *(short8*)(sT + c * 128 + piece * 64 + r * 8) = v;
  }
  __syncthreads();
  int tok = t >> 1, half = t & 1, c0 = half * 96;
  size_t gtok = ((size_t)(b * 256 + wi * 16 + wj0 + (tok >> 6))) * 64 + (tok & 63);
  unsigned short* xwp = xw + gtok * 192 + c0;
  float sum = 0.f, sq = 0.f;
  #pragma unroll
  for (int j8 = 0; j8 < 12; ++j8) {
    unsigned short raw[8];
    unsigned pk[4];
    #pragma unroll
    for (int e = 0; e < 8; ++e) {
      unsigned short rv = sT[(c0 + j8 * 8 + e) * 128 + tok];
      raw[e] = rv;
      float x = bf2f(rv);
      sum += x; sq = fmaf(x, x, sq);
    }
    #pragma unroll
    for (int k = 0; k < 4; ++k) pk[k] = (unsigned)raw[2 * k] | ((unsigned)raw[2 * k + 1] << 16);
    uint4_ pv = { pk[0], pk[1], pk[2], pk[3] };
    *(uint4_*)(xwp + j8 * 8) = pv;
  }
  sum += __shfl_xor(sum, 1);
  sq  += __shfl_xor(sq, 1);
  float mu = sum * (1.f / 192.f);
  float var = sq * (1.f / 192.f) - mu * mu;
  float rs = rsqrtf(var + 1e-5f);
  unsigned short* ap = a + gtok * 192 + c0;
  #pragma unroll
  for (int j8 = 0; j8 < 12; ++j8) {
    unsigned pk[4];
    #pragma unroll
    for (int k = 0; k < 4; ++k) {
      int c = c0 + j8 * 8 + k * 2;
      float v0 = (bf2f(sT[c * 128 + tok]) - mu) * rs * s_g[c] + s_b[c];
      float v1 = (bf2f(sT[(c + 1) * 128 + tok]) - mu) * rs * s_g[c + 1] + s_b[c + 1];
      pk[k] = pack2bf(v0, v1);
    }
    uint4_ pv = { pk[0], pk[1], pk[2], pk[3] };
    *(uint4_*)(ap + j8 * 8) = pv;
  }
}

// ---------------- K2+K3 fused: merged QKV GEMM + windowed attention ----------------
// 6 waves (1/head), 72KB LDS, (384,1). Merged single-pass GEMM: acc[3][2][4],
// af loads 72->24 per wave, one prefetch pipeline. Per-sel ks order unchanged -> bit-identical.
__global__ __launch_bounds__(384, 1) void k_qkvattn(
    const unsigned short* __restrict__ a, const unsigned short* __restrict__ wT,
    const float* __restrict__ qbias, const float* __restrict__ biasAll,
    unsigned short* __restrict__ outO) {
  __shared__ __align__(16) unsigned short sQK[6][4096];  // per head: Q[64][32] | K[64][32]; later P[64][64]
  __shared__ __align__(16) unsigned short sVT[6][2048];  // per head: V^T [32][64]
  int t = threadIdx.x, lane = t & 63, head = t / 64;
  int win = blockIdx.x;
  int wi = (win >> 4) & 15, wj = win & 15;
  int lrow = lane & 15, lkgrp = lane >> 4, lk = lkgrp * 8;
  const unsigned short* aWin = a + (size_t)win * (64 * 192);
  const unsigned short* wbase = wT + (size_t)head * 32 * 192;
  char* qk = (char*)sQK[head];
  char* vt = (char*)sVT[head];

  // ---- merged QKV GEMM: acc[sel][nb][mi] ----
  float4_ acc[3][2][4];
  #pragma unroll
  for (int s = 0; s < 3; ++s)
    #pragma unroll
    for (int nb = 0; nb < 2; ++nb)
      #pragma unroll
      for (int mi = 0; mi < 4; ++mi) acc[s][nb][mi] = (float4_){0.f, 0.f, 0.f, 0.f};
  short8 bwA[6], bwB[6], af0[4], af1[4];
  #pragma unroll
  for (int sn = 0; sn < 6; ++sn)
    bwA[sn] = *(const short8*)(wbase + (size_t)((sn >> 1) * 192 + (sn & 1) * 16 + lrow) * 192 + lk);
  #pragma unroll
  for (int mi = 0; mi < 4; ++mi)
    af0[mi] = *(const short8*)(aWin + (size_t)(mi * 16 + lrow) * 192 + lk);
  #pragma unroll
  for (int sn = 0; sn < 6; ++sn)
    bwB[sn] = *(const short8*)(wbase + (size_t)((sn >> 1) * 192 + (sn & 1) * 16 + lrow) * 192 + 32 + lk);
  #pragma unroll
  for (int mi = 0; mi < 4; ++mi)
    af1[mi] = *(const short8*)(aWin + (size_t)(mi * 16 + lrow) * 192 + 32 + lk);
  #pragma unroll
  for (int ks = 0; ks < 6; ++ks) {
    #pragma unroll
    for (int mi = 0; mi < 4; ++mi) {
      short8 a_ = (ks & 1) ? af1[mi] : af0[mi];
      #pragma unroll
      for (int sn = 0; sn < 6; ++sn) {
        short8 b_ = (ks & 1) ? bwB[sn] : bwA[sn];
        acc[sn >> 1][sn & 1][mi] =
            __builtin_amdgcn_mfma_f32_16x16x32_bf16(b_, a_, acc[sn >> 1][sn & 1][mi], 0, 0, 0);
      }
    }
    if (ks < 4) {
      int kc = (ks + 2) * 32 + lk;
      #pragma unroll
      for (int sn = 0; sn < 6; ++sn) {
        short8 nv = *(const short8*)(wbase + (size_t)((sn >> 1) * 192 + (sn & 1) * 16 + lrow) * 192 + kc);
        if (ks & 1) bwB[sn] = nv; else bwA[sn] = nv;
      }
      #pragma unroll
      for (int mi = 0; mi < 4; ++mi) {
        short8 nv = *(const short8*)(aWin + (size_t)(mi * 16 + lrow) * 192 + kc);
        if (ks & 1) af1[mi] = nv; else af0[mi] = nv;
      }
    }
  }
  // ---- writeout: D[d = nb*16+lkgrp*4+e][tok = mi*16+lrow] ----
  #pragma unroll
  for (int sel = 0; sel < 2; ++sel) {
    #pragma unroll
    for (int nb = 0; nb < 2; ++nb) {
      float4_ b4 = *(const float4_*)(qbias + sel * 192 + head * 32 + nb * 16 + lkgrp * 4);
      int dsub2 = (nb * 16 + lkgrp * 4) * 2;
      #pragma unroll
      for (int mi = 0; mi < 4; ++mi) {
        int tok = mi * 16 + lrow;
        uint2_ pv = { pack2bfc(acc[sel][nb][mi][0] + b4[0], acc[sel][nb][mi][1] + b4[1]),
                      pack2bfc(acc[sel][nb][mi][2] + b4[2], acc[sel][nb][mi][3] + b4[3]) };
        *(uint2_*)(qk + sel * 4096 + ((tok * 64 + dsub2) ^ ((tok & 7) << 4))) = pv;
      }
    }
  }
  #pragma unroll
  for (int nb = 0; nb < 2; ++nb) {
    float4_ b4 = *(const float4_*)(qbias + 384 + head * 32 + nb * 16 + lkgrp * 4);
    #pragma unroll
    for (int mi = 0; mi < 4; ++mi) {
      int tok = mi * 16 + lrow;
      #pragma unroll
      for (int e = 0; e < 4; ++e) {
        int d = nb * 16 + lkgrp * 4 + e;
        *(unsigned short*)(vt + ((d * 128 + tok * 2) ^ ((d & 7) << 4))) =
            f2bfc(acc[2][nb][mi][e] + b4[e]);
      }
    }
  }

  // --- S = Q K^T ---
  short8 kf[4];
  #pragma unroll
  for (int ni = 0; ni < 4; ++ni) {
    int tokk = ni * 16 + lrow;
    kf[ni] = *(const short8*)(qk + 4096 + ((tokk * 64 + lk * 2) ^ ((tokk & 7) << 4)));
  }
  float4_ s[4][4];
  __builtin_amdgcn_s_setprio(1);
  #pragma unroll
  for (int mi = 0; mi < 4; ++mi) {
    int tokq = mi * 16 + lrow;
    short8 qf = *(const short8*)(qk + ((tokq * 64 + lk * 2) ^ ((tokq & 7) << 4)));
    #pragma unroll
    for (int ni = 0; ni < 4; ++ni) {
      s[mi][ni] = (float4_){0.f, 0.f, 0.f, 0.f};
      s[mi][ni] = __builtin_amdgcn_mfma_f32_16x16x32_bf16(qf, kf[ni], s[mi][ni], 0, 0, 0);
    }
  }
  __builtin_amdgcn_s_setprio(0);
  // --- softmax -> P over qk region ---
  const float* bh = biasAll + head * 4096;
  bool wi15 = (wi == 15), wj15 = (wj == 15);
  bool edge = wi15 || wj15;
  #pragma unroll
  for (int mi = 0; mi < 4; ++mi) {
    #pragma unroll
    for (int e = 0; e < 4; ++e) {
      int row = mi * 16 + lkgrp * 4 + e;
      int rcls = (wi15 ? ((row >> 3) >= 4 ? 2 : 1) : 0) * 3 +
                 (wj15 ? ((row & 7) >= 4 ? 2 : 1) : 0);
      float v[4];
      #pragma unroll
      for (int ni = 0; ni < 4; ++ni) {
        int col = ni * 16 + lrow;
        float xv = s[mi][ni][e] + bh[row * 64 + col];
        if (edge) {
          int ccls = (wi15 ? ((col >> 3) >= 4 ? 2 : 1) : 0) * 3 +
                     (wj15 ? ((col & 7) >= 4 ? 2 : 1) : 0);
          if (ccls != rcls) xv -= 100.f;
        }
        v[ni] = xv;
      }
      float mx = fmaxf(fmaxf(v[0], v[1]), fmaxf(v[2], v[3]));
      mx = fmaxf(mx, __shfl_xor(mx, 1));
      mx = fmaxf(mx, __shfl_xor(mx, 2));
      mx = fmaxf(mx, __shfl_xor(mx, 4));
      mx = fmaxf(mx, __shfl_xor(mx, 8));
      float sm = 0.f;
      #pragma unroll
      for (int ni = 0; ni < 4; ++ni) { v[ni] = __expf(v[ni] - mx); sm += v[ni]; }
      sm += __shfl_xor(sm, 1);
      sm += __shfl_xor(sm, 2);
      sm += __shfl_xor(sm, 4);
      sm += __shfl_xor(sm, 8);
      float inv = 1.f / sm;
      #pragma unroll
      for (int ni = 0; ni < 4; ++ni) {
        int col = ni * 16 + lrow;
        *(unsigned short*)(qk + ((row * 128 + col * 2) ^ ((row & 7) << 4))) = f2bfc(v[ni] * inv);
      }
    }
  }
  // --- O^T = V^T @ P^T ---
  float4_ o[2][4];
  #pragma unroll
  for (int db = 0; db < 2; ++db)
    #pragma unroll
    for (int qb2 = 0; qb2 < 4; ++qb2) o[db][qb2] = (float4_){0.f, 0.f, 0.f, 0.f};
  __builtin_amdgcn_s_setprio(1);
  #pragma unroll
  for (int kk = 0; kk < 2; ++kk) {
    int ktok = kk * 32 + lk;
    short8 vf[2], pf[4];
    #pragma unroll
    for (int db = 0; db < 2; ++db) {
      int d = db * 16 + lrow;
      vf[db] = *(const short8*)(vt + ((d * 128 + ktok * 2) ^ ((d & 7) << 4)));
    }
    #pragma unroll
    for (int qb2 = 0; qb2 < 4; ++qb2) {
      int rq = qb2 * 16 + lrow;
      pf[qb2] = *(const short8*)(qk + ((rq * 128 + ktok * 2) ^ ((rq & 7) << 4)));
    }
    #pragma unroll
    for (int db = 0; db < 2; ++db)
      #pragma unroll
      for (int qb2 = 0; qb2 < 4; ++qb2)
        o[db][qb2] = __builtin_amdgcn_mfma_f32_16x16x32_bf16(vf[db], pf[qb2], o[db][qb2], 0, 0, 0);
  }
  __builtin_amdgcn_s_setprio(0);
  unsigned short* ob = outO + (size_t)win * (64 * 192);
  #pragma unroll
  for (int qb2 = 0; qb2 < 4; ++qb2)
    #pragma unroll
    for (int db = 0; db < 2; ++db) {
      unsigned lo = pack2bfc(o[db][qb2][0], o[db][qb2][1]);
      unsigned hi = pack2bfc(o[db][qb2][2], o[db][qb2][3]);
      uint2_ pv = { lo, hi };
      *(uint2_*)(ob + (size_t)(qb2 * 16 + lrow) * 192 + head * 32 + db * 16 + lkgrp * 4) = pv;
    }
}

// ---------------- K4: proj + residual + LN2 + MLP(GELU) + residual + un-window ----------------
// (256,2). w1 phase accumulates ALL ni at once (h1[4][3]) -> sH reads 72->24 per chunk;
// rolling per-ks w1 weight buffers; next-chunk preload hidden under w2 phase. sB2 dbuf.
__global__ __launch_bounds__(256, 2) void k_mlp(
    const unsigned short* __restrict__ O, const unsigned short* __restrict__ xw,
    const unsigned short* __restrict__ projWT, const float* __restrict__ proj_b,
    const float* __restrict__ n2g, const float* __restrict__ n2b,
    const unsigned short* __restrict__ w1T, const float* __restrict__ mlpb1,
    const unsigned short* __restrict__ w2T, const float* __restrict__ mlpb2,
    float* __restrict__ y) {
  __shared__ __align__(16) unsigned short sH[64 * 192];
  __shared__ __align__(16) unsigned short sB2[2][64 * 192];
  __shared__ float sRed[64 * 8];
  __shared__ unsigned sTok[64];
  int t = threadIdx.x, lane = t & 63, wn = t >> 6;
  int lrow = lane & 15, lkgrp = lane >> 4, lk = lkgrp * 8;
  int blk = blockIdx.x;
  int b = blk >> 8, rem = blk & 255, ta = rem >> 3, tb_ = rem & 7;
  if (t < 64) {
    int rr = t >> 4, ss = t & 15;
    int h = ta * 4 + rr, w = tb_ * 16 + ss;
    int hp = (h + 124) & 127, wp = (w + 124) & 127;
    unsigned gtok = ((unsigned)(b * 256 + (hp >> 3) * 16 + (wp >> 3))) * 64 +
                    (hp & 7) * 8 + (wp & 7);
    sTok[t] = gtok * 192u;
  }
  __syncthreads();
  unsigned aoff[4];
  #pragma unroll
  for (int mi = 0; mi < 4; ++mi) aoff[mi] = sTok[mi * 16 + lrow];
  // ---- proj: rolling prefetch with gathered A rows ----
  float4_ tacc[4][3];
  #pragma unroll
  for (int mi = 0; mi < 4; ++mi)
    #pragma unroll
    for (int ni = 0; ni < 3; ++ni) tacc[mi][ni] = (float4_){0.f, 0.f, 0.f, 0.f};
  {
    short8 bP0[3][3], bP1[3][3], af0[4], af1[4];
    #pragma unroll
    for (int ni = 0; ni < 3; ++ni)
      #pragma unroll
      for (int k3 = 0; k3 < 3; ++k3)
        bP0[ni][k3] = *(const short8*)(projWT + (size_t)(wn * 48 + ni * 16 + lrow) * 192 + k3 * 32 + lk);
    #pragma unroll
    for (int mi = 0; mi < 4; ++mi)
      af0[mi] = *(const short8*)(O + aoff[mi] + lk);
    #pragma unroll
    for (int ni = 0; ni < 3; ++ni)
      #pragma unroll
      for (int k3 = 0; k3 < 3; ++k3)
        bP1[ni][k3] = *(const short8*)(projWT + (size_t)(wn * 48 + ni * 16 + lrow) * 192 + (3 + k3) * 32 + lk);
    #pragma unroll
    for (int mi = 0; mi < 4; ++mi)
      af1[mi] = *(const short8*)(O + aoff[mi] + 32 + lk);
    #pragma unroll
    for (int ks = 0; ks < 6; ++ks) {
      #pragma unroll
      for (int mi = 0; mi < 4; ++mi) {
        short8 a_ = (ks & 1) ? af1[mi] : af0[mi];
        #pragma unroll
        for (int ni = 0; ni < 3; ++ni) {
          short8 b_ = (ks < 3) ? bP0[ni][ks] : bP1[ni][ks - 3];
          tacc[mi][ni] = __builtin_amdgcn_mfma_f32_16x16x32_bf16(a_, b_, tacc[mi][ni], 0, 0, 0);
        }
      }
      if (ks < 4) {
        #pragma unroll
        for (int mi = 0; mi < 4; ++mi) {
          short8 nv = *(const short8*)(O + aoff[mi] + (ks + 2) * 32 + lk);
          if (ks & 1) af1[mi] = nv; else af0[mi] = nv;
        }
      }
    }
  }
  // ---- residual: batched gathered xw loads ----
  {
    unsigned roff[4][4];
    #pragma unroll
    for (int mi = 0; mi < 4; ++mi)
      #pragma unroll
      for (int e = 0; e < 4; ++e)
        roff[mi][e] = sTok[mi * 16 + lkgrp * 4 + e];
    unsigned short rxv[3][4][4];
    #pragma unroll
    for (int ni = 0; ni < 3; ++ni) {
      int col = wn * 48 + ni * 16 + lrow;
      #pragma unroll
      for (int mi = 0; mi < 4; ++mi)
        #pragma unroll
        for (int e = 0; e < 4; ++e)
          rxv[ni][mi][e] = xw[roff[mi][e] + col];
    }
    #pragma unroll
    for (int ni = 0; ni < 3; ++ni) {
      float pbv = proj_b[wn * 48 + ni * 16 + lrow];
      #pragma unroll
      for (int mi = 0; mi < 4; ++mi)
        #pragma unroll
        for (int e = 0; e < 4; ++e)
          tacc[mi][ni][e] += pbv + bf2f(rxv[ni][mi][e]);
    }
  }
  // ---- LN2 ----
  #pragma unroll
  for (int mi = 0; mi < 4; ++mi)
    #pragma unroll
    for (int e = 0; e < 4; ++e) {
      float s1 = tacc[mi][0][e] + tacc[mi][1][e] + tacc[mi][2][e];
      float s2 = tacc[mi][0][e] * tacc[mi][0][e] + tacc[mi][1][e] * tacc[mi][1][e] +
                 tacc[mi][2][e] * tacc[mi][2][e];
      s1 += __shfl_xor(s1, 1); s1 += __shfl_xor(s1, 2); s1 += __shfl_xor(s1, 4); s1 += __shfl_xor(s1, 8);
      s2 += __shfl_xor(s2, 1); s2 += __shfl_xor(s2, 2); s2 += __shfl_xor(s2, 4); s2 += __shfl_xor(s2, 8);
      if (lrow == 0) {
        int row = mi * 16 + lkgrp * 4 + e;
        sRed[row * 8 + wn * 2 + 0] = s1;
        sRed[row * 8 + wn * 2 + 1] = s2;
      }
    }
  __syncthreads();
  #pragma unroll
  for (int mi = 0; mi < 4; ++mi)
    #pragma unroll
    for (int e = 0; e < 4; ++e) {
      int row = mi * 16 + lkgrp * 4 + e;
      float s1 = sRed[row * 8] + sRed[row * 8 + 2] + sRed[row * 8 + 4] + sRed[row * 8 + 6];
      float s2 = sRed[row * 8 + 1] + sRed[row * 8 + 3] + sRed[row * 8 + 5] + sRed[row * 8 + 7];
      float mu = s1 * (1.f / 192.f);
      float var = s2 * (1.f / 192.f) - mu * mu;
      float rs = rsqrtf(var + 1e-5f);
      #pragma unroll
      for (int ni = 0; ni < 3; ++ni) {
        int col = wn * 48 + ni * 16 + lrow;
        float hv = (tacc[mi][ni][e] - mu) * rs * n2g[col] + n2b[col];
        *(unsigned short*)((char*)sH + ((row * 384 + col * 2) ^ ((row & 7) << 4))) = f2bfc(hv);
      }
    }
  __syncthreads();
  // ---- MLP: w1 all-ni accumulation, rolling per-ks weights; w2 half-batched; sB2 dbuf ----
  short8 wA[3], wB[3];
  #pragma unroll
  for (int ni = 0; ni < 3; ++ni)
    wA[ni] = *(const short8*)(w1T + (size_t)(wn * 48 + ni * 16 + lrow) * 192 + lk);
  #pragma unroll
  for (int ni = 0; ni < 3; ++ni)
    wB[ni] = *(const short8*)(w1T + (size_t)(wn * 48 + ni * 16 + lrow) * 192 + 32 + lk);
  #pragma unroll 1
  for (int ch = 0; ch < 4; ++ch) {
    char* sBc = (char*)sB2[ch & 1];
    float4_ h1[4][3];
    #pragma unroll
    for (int mi = 0; mi < 4; ++mi)
      #pragma unroll
      for (int ni = 0; ni < 3; ++ni) h1[mi][ni] = (float4_){0.f, 0.f, 0.f, 0.f};
    __builtin_amdgcn_s_setprio(1);
    #pragma unroll
    for (int ks = 0; ks < 6; ++ks) {
      int kb = ks * 32 + lk;
      #pragma unroll
      for (int mi = 0; mi < 4; ++mi) {
        int row = mi * 16 + lrow;
        short8 afv = *(const short8*)((const char*)sH + ((row * 384 + kb * 2) ^ ((row & 7) << 4)));
        #pragma unroll
        for (int ni = 0; ni < 3; ++ni) {
          short8 b_ = (ks & 1) ? wB[ni] : wA[ni];
          h1[mi][ni] = __builtin_amdgcn_mfma_f32_16x16x32_bf16(b_, afv, h1[mi][ni], 0, 0, 0);
        }
      }
      if (ks < 4) {
        int kc = (ks + 2) * 32 + lk;
        #pragma unroll
        for (int ni = 0; ni < 3; ++ni) {
          short8 nv = *(const short8*)(w1T + (size_t)(ch * 192 + wn * 48 + ni * 16 + lrow) * 192 + kc);
          if (ks & 1) wB[ni] = nv; else wA[ni] = nv;
        }
      }
    }
    __builtin_amdgcn_s_setprio(0);
    // gelu writeout: D[n = ni*16+lkgrp*4+e][tok = mi*16+lrow] -> packed 8B stores
    #pragma unroll
    for (int ni = 0; ni < 3; ++ni) {
      float4_ b4 = *(const float4_*)(mlpb1 + ch * 192 + wn * 48 + ni * 16 + lkgrp * 4);
      int nsub2 = (wn * 48 + ni * 16 + lkgrp * 4) * 2;
      #pragma unroll
      for (int mi = 0; mi < 4; ++mi) {
        int tok_ = mi * 16 + lrow;
        float g0 = gelu_f(h1[mi][ni][0] + b4[0]);
        float g1 = gelu_f(h1[mi][ni][1] + b4[1]);
        float g2 = gelu_f(h1[mi][ni][2] + b4[2]);
        float g3 = gelu_f(h1[mi][ni][3] + b4[3]);
        uint2_ pv = { pack2bfc(g0, g1), pack2bfc(g2, g3) };
        *(uint2_*)(sBc + ((tok_ * 384 + nsub2) ^ ((tok_ & 7) << 4))) = pv;
      }
    }
    // w2 weights (half-batched) + next-chunk w1 ks0/ks1 preload under this phase
    short8 cw0[3][3], cw1[3][3];
    #pragma unroll
    for (int ni = 0; ni < 3; ++ni)
      #pragma unroll
      for (int k3 = 0; k3 < 3; ++k3)
        cw0[ni][k3] = *(const short8*)(w2T + (size_t)(wn * 48 + ni * 16 + lrow) * 768 + ch * 192 + k3 * 32 + lk);
    __syncthreads();
    #pragma unroll
    for (int ni = 0; ni < 3; ++ni)
      #pragma unroll
      for (int k3 = 0; k3 < 3; ++k3)
        cw1[ni][k3] = *(const short8*)(w2T + (size_t)(wn * 48 + ni * 16 + lrow) * 768 + ch * 192 + (3 + k3) * 32 + lk);
    if (ch < 3) {
      int gb = (ch + 1) * 192 + wn * 48;
      #pragma unroll
      for (int ni = 0; ni < 3; ++ni)
        wA[ni] = *(const short8*)(w1T + (size_t)(gb + ni * 16 + lrow) * 192 + lk);
      #pragma unroll
      for (int ni = 0; ni < 3; ++ni)
        wB[ni] = *(const short8*)(w1T + (size_t)(gb + ni * 16 + lrow) * 192 + 32 + lk);
    }
    __builtin_amdgcn_s_setprio(1);
    #pragma unroll
    for (int ks = 0; ks < 6; ++ks) {
      int kb = ks * 32 + lk;
      short8 af[4];
      #pragma unroll
      for (int mi = 0; mi < 4; ++mi) {
        int row = mi * 16 + lrow;
        af[mi] = *(const short8*)(sBc + ((row * 384 + kb * 2) ^ ((row & 7) << 4)));
      }
      #pragma unroll
      for (int mi = 0; mi < 4; ++mi)
        #pragma unroll
        for (int ni = 0; ni < 3; ++ni) {
          short8 b_ = (ks < 3) ? cw0[ni][ks] : cw1[ni][ks - 3];
          tacc[mi][ni] = __builtin_amdgcn_mfma_f32_16x16x32_bf16(af[mi], b_, tacc[mi][ni], 0, 0, 0);
        }
    }
    __builtin_amdgcn_s_setprio(0);
    // no end-of-chunk barrier: sB2 double-buffered; reuse ordered by next chunk's pre-w2 barrier.
  }
  // ---- epilogue: +mlp_b2, aligned full-line y stores ----
  int wcol = tb_ * 16 + lkgrp * 4;
  #pragma unroll
  for (int ni = 0; ni < 3; ++ni) {
    int col = wn * 48 + ni * 16 + lrow;
    float b2v = mlpb2[col];
    #pragma unroll
    for (int mi = 0; mi < 4; ++mi) {
      int h = ta * 4 + mi;
      float4_ vv;
      #pragma unroll
      for (int e = 0; e < 4; ++e) vv[e] = tacc[mi][ni][e] + b2v;
      *(float4_*)(y + ((size_t)(b * 192 + col) * 128 + h) * 128 + wcol) = vv;
    }
  }
}

extern "C" void kernel_launch(void* const* d_in, const int* in_sizes, int n_in,
                              void* d_out, int out_size, void* d_ws, size_t ws_size,
                              hipStream_t stream) {
  (void)in_sizes; (void)n_in; (void)out_size;
  const float* x    = (const float*)d_in[0];
  const float* pcw  = (const float*)d_in[1];
  const float* n1g  = (const float*)d_in[2];
  const float* n1b  = (const float*)d_in[3];
  const float* qkvw = (const float*)d_in[4];
  const float* qkvb = (const float*)d_in[5];
  const float* pw   = (const float*)d_in[6];
  const float* pb   = (const float*)d_in[7];
  const float* relt = (const float*)d_in[8];
  const float* n2g  = (const float*)d_in[9];
  const float* n2b  = (const float*)d_in[10];
  const float* w1   = (const float*)d_in[11];
  const float* mb1  = (const float*)d_in[12];
  const float* w2   = (const float*)d_in[13];
  const float* mb2  = (const float*)d_in[14];
  float* y = (float*)d_out;
  char* ws = (char*)d_ws;
  size_t off = 0;
  auto carve = [&](size_t bytes) { void* p = ws + off; off += (bytes + 255) & ~(size_t)255; return p; };
  unsigned short* qkvWT  = (unsigned short*)carve(576 * 192 * 2);
  unsigned short* projWT = (unsigned short*)carve(192 * 192 * 2);
  unsigned short* w1T    = (unsigned short*)carve(768 * 192 * 2);
  unsigned short* w2T    = (unsigned short*)carve(192 * 768 * 2);
  float* qkv_b_s   = (float*)carve(576 * 4);
  float* bias_attn = (float*)carve(6 * 64 * 64 * 4);
  unsigned short* aBuf   = (unsigned short*)carve((size_t)131072 * 192 * 2);
  unsigned short* xwBuf  = (unsigned short*)carve((size_t)131072 * 192 * 2);
  unsigned short* temp   = (unsigned short*)carve((size_t)131072 * 192 * 2); // conv temp, then O
  if (off > ws_size) return;

  k_prep<<<dim3(1827), dim3(256), 0, stream>>>(qkvw, qkvb, pw, w1, w2, relt,
                                               qkvWT, projWT, w1T, w2T, qkv_b_s, bias_attn);
  k_conv<<<dim3(384, 8), dim3(256), 0, stream>>>(x, pcw, temp);
  k_lnw<<<dim3(8, 16, 8), dim3(256), 0, stream>>>(temp, n1g, n1b, xwBuf, aBuf);
  k_qkvattn<<<dim3(2048), dim3(384), 0, stream>>>(aBuf, qkvWT, qkv_b_s, bias_attn, temp);
  k_mlp<<<dim3(2048), dim3(256), 0, stream>>>(temp, xwBuf, projWT, pb, n2g, n2b,
                                              w1T, mb1, w2T, mb2, y);
}